// Round 7
// baseline (1147.564 us; speedup 1.0000x reference)
//
#include <hip/hip_runtime.h>
#include <math.h>

#define BB 2
#define SS 2048
#define HIDD 1024
#define NHH 16
#define HDD 64

using f4 = __attribute__((ext_vector_type(4))) float;
using short8 = __attribute__((ext_vector_type(8))) short;   // 8 bf16 (4 VGPRs)
using uint2v = __attribute__((ext_vector_type(2))) unsigned int;

__device__ inline unsigned short bf16_rne(float x) {
    unsigned u = __builtin_bit_cast(unsigned, x);
    u += 0x7FFFu + ((u >> 16) & 1u);
    return (unsigned short)(u >> 16);
}
__device__ inline float bf16_tof(unsigned short h) {
    unsigned u = ((unsigned)h) << 16;
    return __builtin_bit_cast(float, u);
}

// ----------------------------------------------------------------------
// GEMM: C = A[M,K] @ W[K,N] + bias[N]   (M=4096, N=K=1024)  — unchanged
// (validated round 4 as part of the 843us run)
template<int OUT_MODE>
__global__ __launch_bounds__(256)
void gemm_kernel(const float* __restrict__ A, const float* __restrict__ W,
                 const float* __restrict__ bias, float* __restrict__ C)
{
    constexpr int M = BB * SS, N = HIDD, K = HIDD;
    constexpr int BM = 128, BN = 64, BK = 16, NK = K / BK;
    constexpr int LDA = 132, LDW = 68;
    __shared__ float As[2][BK][LDA];
    __shared__ float Ws[2][BK][LDW];

    const int tid = threadIdx.x;
    const int tx = tid & 15, ty = tid >> 4;

    const int swz = (blockIdx.x & 7) * 64 + (blockIdx.x >> 3);
    const int n0 = (swz & 15) * BN;
    const int m0 = (swz >> 4) * BM;

    const int a_m = tid >> 2;
    const int a_k = (tid & 3) * 4;
    const int w_k = tid >> 4;
    const int w_n = (tid & 15) * 4;

    const float* Abase = A + (size_t)m0 * K;
    const float* Wbase = W + n0;

    f4 pa0, pa1, pw0;

#define G_LOAD(kt) {                                                        \
    const float* Ap = Abase + (size_t)(kt) * BK + a_k;                      \
    pa0 = *(const f4*)(Ap + (size_t)a_m * K);                               \
    pa1 = *(const f4*)(Ap + (size_t)(a_m + 64) * K);                        \
    pw0 = *(const f4*)(Wbase + (size_t)((kt) * BK + w_k) * N + w_n); }

#define LDS_WRITE(buf) {                                                    \
    As[buf][a_k+0][a_m]      = pa0[0]; As[buf][a_k+1][a_m]      = pa0[1];   \
    As[buf][a_k+2][a_m]      = pa0[2]; As[buf][a_k+3][a_m]      = pa0[3];   \
    As[buf][a_k+0][a_m+64]   = pa1[0]; As[buf][a_k+1][a_m+64]   = pa1[1];   \
    As[buf][a_k+2][a_m+64]   = pa1[2]; As[buf][a_k+3][a_m+64]   = pa1[3];   \
    *(f4*)&Ws[buf][w_k][w_n] = pw0; }

    float acc[8][4] = {};

    G_LOAD(0);
    LDS_WRITE(0);
    __syncthreads();

    int cur = 0;
    for (int kt = 0; kt < NK; ++kt) {
        if (kt + 1 < NK) G_LOAD(kt + 1);
        #pragma unroll 4
        for (int k = 0; k < BK; ++k) {
            f4 af0 = *(const f4*)&As[cur][k][4 * ty];
            f4 af1 = *(const f4*)&As[cur][k][64 + 4 * ty];
            f4 bf  = *(const f4*)&Ws[cur][k][4 * tx];
            #pragma unroll
            for (int i = 0; i < 4; ++i) {
                #pragma unroll
                for (int j = 0; j < 4; ++j) {
                    acc[i][j]   = fmaf(af0[i], bf[j], acc[i][j]);
                    acc[i+4][j] = fmaf(af1[i], bf[j], acc[i+4][j]);
                }
            }
        }
        if (kt + 1 < NK) LDS_WRITE(cur ^ 1);
        __syncthreads();
        cur ^= 1;
    }

    f4 biasv = *(const f4*)&bias[n0 + 4 * tx];
    #pragma unroll
    for (int i = 0; i < 8; ++i) {
        const int m = m0 + 4 * ty + ((i < 4) ? i : (64 + i - 4));
        f4 v;
        #pragma unroll
        for (int j = 0; j < 4; ++j) v[j] = acc[i][j] + biasv[j];
        if (OUT_MODE == 0) {
            *(f4*)(C + (size_t)m * N + n0 + 4 * tx) = v;
        } else {
            const int b = m >> 11, s = m & (SS - 1);
            const int na = n0 + 4 * tx;
            float* da = C + ((size_t)(b * NHH + (na >> 6)) * SS + s) * HDD + (na & 63);
            *(f4*)da = v;
        }
    }
#undef G_LOAD
#undef LDS_WRITE
}

// ----------------------------------------------------------------------
// Flash attention, k=v=q, floored scores.
// QK^T: exact fp32 VALU (floor safety), Q held in 64 VGPRs (block-constant,
// prescaled 1/8; FMA order identical to validated round-3 run -> scores
// bit-identical -> floor flips unchanged).
// PV: bf16 2-split, 3-term MFMA (mirrored A/B frag loads; k-permutation
// cancels between A and B).
// LDS 54272 B (<= 64KB static limit; round-5's 70KB may have been the
// launch failure): k_t f32[64][68], P_hi/P_lo/Vt_hi/Vt_lo bf16[64][72].
// Stride 72 shorts: quarter-wave frag-read bank = (4lr+4lh)%32 -> 2-way
// (free, m136). Rows 144B = 9*16B: b128-aligned.
__global__ __launch_bounds__(256)
void attn_kernel(const float* __restrict__ q, float* __restrict__ o)
{
    __shared__ float k_t[64][68];
    __shared__ unsigned short P_hi[64][72];
    __shared__ unsigned short P_lo[64][72];
    __shared__ unsigned short Vt_hi[64][72];
    __shared__ unsigned short Vt_lo[64][72];

    const int tid = threadIdx.x;
    const int tx = tid & 15, ty = tid >> 4;
    const int lane = tid & 63;
    const int wv = tid >> 6;           // wave 0..3
    const int lr = lane & 15, lh = lane >> 4;

    // XCD-aware bijective remap: 1024 blocks = 8 XCDs x 128
    const int swzb = (blockIdx.x & 7) * 128 + (blockIdx.x >> 3);
    const int qb = swzb & 31;
    const int bh = swzb >> 5;

    const float* qhead = q + (size_t)bh * SS * 64;

    const int st_r = tid >> 2;             // key row 0..63
    const int st_w = (tid & 3) * 4;        // d-chunk base

    // ---- Q rows 4ty..4ty+3 into registers (prescaled by 1/8, exact) ----
    f4 qreg[4][16];
    {
        const float* src = qhead + (size_t)(qb * 64 + 4 * ty) * 64;
        #pragma unroll
        for (int i = 0; i < 4; ++i)
            #pragma unroll
            for (int w = 0; w < 16; ++w) {
                f4 vq = *(const f4*)(src + (size_t)i * 64 + 4 * w);
                #pragma unroll
                for (int j = 0; j < 4; ++j) vq[j] *= 0.125f;
                qreg[i][w] = vq;
            }
    }

    f4 acc[4] = {};   // MFMA C-frags: acc[ct][i] = O[4ty+i][16ct+lr]
    float m_r[4] = {-1e30f, -1e30f, -1e30f, -1e30f};
    float l_r[4] = {};

    f4 pk[4];
    {
        const float* src = qhead + (size_t)st_r * 64 + st_w * 4;
        #pragma unroll
        for (int i = 0; i < 4; ++i) pk[i] = *(const f4*)(src + 4 * i);
    }

    for (int kt = 0; kt < SS / 64; ++kt) {
        __syncthreads();   // prev tile's QK/PV done with k_t/Vt
        // ---- stage K tile: k_t f32 transposed + Vt bf16-split transposed ----
        #pragma unroll
        for (int i = 0; i < 4; ++i) {
            #pragma unroll
            for (int j = 0; j < 4; ++j) {
                const int d = (st_w + i) * 4 + j;
                const float v = pk[i][j];
                k_t[d][st_r] = v;
                const unsigned short h = bf16_rne(v);
                Vt_hi[d][st_r] = h;
                Vt_lo[d][st_r] = bf16_rne(v - bf16_tof(h));
            }
        }
        __syncthreads();
        // prefetch next K tile (hidden under QK+softmax+PV)
        if (kt + 1 < SS / 64) {
            const float* src = qhead + (size_t)((kt + 1) * 64 + st_r) * 64 + st_w * 4;
            #pragma unroll
            for (int i = 0; i < 4; ++i) pk[i] = *(const f4*)(src + 4 * i);
        }

        // ---- QK^T (exact fp32): sc[i][j] = (q/8)[4ty+i] . k[4tx+j] ----
        float sc[4][4] = {};
        #pragma unroll
        for (int w = 0; w < 16; ++w) {
            f4 kf[4];
            #pragma unroll
            for (int l = 0; l < 4; ++l) kf[l] = *(const f4*)&k_t[4 * w + l][4 * tx];
            #pragma unroll
            for (int l = 0; l < 4; ++l)
                #pragma unroll
                for (int i = 0; i < 4; ++i)
                    #pragma unroll
                    for (int j = 0; j < 4; ++j)
                        sc[i][j] = fmaf(qreg[i][w][l], kf[l][j], sc[i][j]);
        }

        // ---- floored scores + online softmax + P bf16 split ----
        #pragma unroll
        for (int i = 0; i < 4; ++i) {
            #pragma unroll
            for (int j = 0; j < 4; ++j) sc[i][j] = floorf(sc[i][j]);
            float mx = fmaxf(fmaxf(sc[i][0], sc[i][1]), fmaxf(sc[i][2], sc[i][3]));
            #pragma unroll
            for (int s = 1; s < 16; s <<= 1) mx = fmaxf(mx, __shfl_xor(mx, s, 16));
            const float mn = fmaxf(m_r[i], mx);
            const float corr = __expf(m_r[i] - mn);
            m_r[i] = mn;
            float p[4], sum = 0.f;
            #pragma unroll
            for (int j = 0; j < 4; ++j) { p[j] = __expf(sc[i][j] - mn); sum += p[j]; }
            #pragma unroll
            for (int s = 1; s < 16; s <<= 1) sum += __shfl_xor(sum, s, 16);
            l_r[i] = l_r[i] * corr + sum;
            // rescale MFMA accumulators (D-reg i == softmax row 4ty+i)
            acc[0][i] *= corr; acc[1][i] *= corr; acc[2][i] *= corr; acc[3][i] *= corr;
            // split P to bf16 hi/lo, store packed
            unsigned short h0 = bf16_rne(p[0]), h1 = bf16_rne(p[1]);
            unsigned short h2 = bf16_rne(p[2]), h3 = bf16_rne(p[3]);
            uint2v uh, ul;
            uh[0] = (unsigned)h0 | ((unsigned)h1 << 16);
            uh[1] = (unsigned)h2 | ((unsigned)h3 << 16);
            unsigned short g0 = bf16_rne(p[0] - bf16_tof(h0));
            unsigned short g1 = bf16_rne(p[1] - bf16_tof(h1));
            unsigned short g2 = bf16_rne(p[2] - bf16_tof(h2));
            unsigned short g3 = bf16_rne(p[3] - bf16_tof(h3));
            ul[0] = (unsigned)g0 | ((unsigned)g1 << 16);
            ul[1] = (unsigned)g2 | ((unsigned)g3 << 16);
            *(uint2v*)&P_hi[4 * ty + i][4 * tx] = uh;
            *(uint2v*)&P_lo[4 * ty + i][4 * tx] = ul;
        }
        // NO barrier: P is wave-private (written by ty in [4wv,4wv+4),
        // read as A-frags rows 16wv+lr — same wave). Within-wave LDS
        // RAW ordering enforced by compiler lgkmcnt.

        // ---- PV via MFMA: 3-term bf16 split ----
        const int prow = 16 * wv + lr;
        short8 ah0 = *(const short8*)&P_hi[prow][lh * 8];
        short8 ah1 = *(const short8*)&P_hi[prow][32 + lh * 8];
        short8 al0 = *(const short8*)&P_lo[prow][lh * 8];
        short8 al1 = *(const short8*)&P_lo[prow][32 + lh * 8];
        #pragma unroll
        for (int ct = 0; ct < 4; ++ct) {
            const int vr = 16 * ct + lr;
            short8 bh0 = *(const short8*)&Vt_hi[vr][lh * 8];
            short8 bh1 = *(const short8*)&Vt_hi[vr][32 + lh * 8];
            short8 bl0 = *(const short8*)&Vt_lo[vr][lh * 8];
            short8 bl1 = *(const short8*)&Vt_lo[vr][32 + lh * 8];
            acc[ct] = __builtin_amdgcn_mfma_f32_16x16x32_bf16(ah0, bh0, acc[ct], 0, 0, 0);
            acc[ct] = __builtin_amdgcn_mfma_f32_16x16x32_bf16(al0, bh0, acc[ct], 0, 0, 0);
            acc[ct] = __builtin_amdgcn_mfma_f32_16x16x32_bf16(ah0, bl0, acc[ct], 0, 0, 0);
            acc[ct] = __builtin_amdgcn_mfma_f32_16x16x32_bf16(ah1, bh1, acc[ct], 0, 0, 0);
            acc[ct] = __builtin_amdgcn_mfma_f32_16x16x32_bf16(al1, bh1, acc[ct], 0, 0, 0);
            acc[ct] = __builtin_amdgcn_mfma_f32_16x16x32_bf16(ah1, bl1, acc[ct], 0, 0, 0);
        }
    }

    // ---- epilogue: normalize rows, write o[b][s][h*64 + 16ct + lr] ----
    const int b = bh >> 4, h = bh & 15;
    #pragma unroll
    for (int i = 0; i < 4; ++i) {
        const float inv = 1.0f / l_r[i];
        const int srow = qb * 64 + 4 * ty + i;
        float* orow = o + ((size_t)(b * SS + srow)) * HIDD + h * 64;
        #pragma unroll
        for (int ct = 0; ct < 4; ++ct)
            orow[16 * ct + lr] = acc[ct][i] * inv;
    }
}

// ----------------------------------------------------------------------
extern "C" void kernel_launch(void* const* d_in, const int* in_sizes, int n_in,
                              void* d_out, int out_size, void* d_ws, size_t ws_size,
                              hipStream_t stream)
{
    const float* x  = (const float*)d_in[0];
    const float* Wq = (const float*)d_in[1];
    const float* bq = (const float*)d_in[2];
    const float* Wo = (const float*)d_in[3];
    const float* bo = (const float*)d_in[4];
    float* out = (float*)d_out;

    float* q_ws    = (float*)d_ws;                       // [B*NH][S][64] = 16 MB
    float* attn_ws = q_ws + (size_t)BB * SS * HIDD;      // [B][S][HID]   = 16 MB

    gemm_kernel<1><<<512, 256, 0, stream>>>(x, Wq, bq, q_ws);
    attn_kernel<<<1024, 256, 0, stream>>>(q_ws, attn_ws);
    gemm_kernel<0><<<512, 256, 0, stream>>>(attn_ws, Wo, bo, out);
}

// Round 12
// 702.418 us; speedup vs baseline: 1.6337x; 1.6337x over previous
//
#include <hip/hip_runtime.h>
#include <math.h>

#define BB 2
#define SS 2048
#define HIDD 1024
#define NHH 16
#define HDD 64

using f4 = __attribute__((ext_vector_type(4))) float;
using short8 = __attribute__((ext_vector_type(8))) short;   // 8 bf16 (4 VGPRs)
using uint2v = __attribute__((ext_vector_type(2))) unsigned int;

__device__ inline unsigned short bf16_rne(float x) {
    unsigned u = __builtin_bit_cast(unsigned, x);
    u += 0x7FFFu + ((u >> 16) & 1u);
    return (unsigned short)(u >> 16);
}
__device__ inline float bf16_tof(unsigned short h) {
    unsigned u = ((unsigned)h) << 16;
    return __builtin_bit_cast(float, u);
}

struct bfrag { short8 hi, lo; };
__device__ inline bfrag split8(const f4 a, const f4 b) {
    bfrag r;
    #pragma unroll
    for (int j = 0; j < 4; ++j) {
        const unsigned short h = bf16_rne(a[j]);
        r.hi[j] = (short)h;
        r.lo[j] = (short)bf16_rne(a[j] - bf16_tof(h));
    }
    #pragma unroll
    for (int j = 0; j < 4; ++j) {
        const unsigned short h = bf16_rne(b[j]);
        r.hi[4 + j] = (short)h;
        r.lo[4 + j] = (short)bf16_rne(b[j] - bf16_tof(h));
    }
    return r;
}

// ----------------------------------------------------------------------
// GEMM: C = A[M,K] @ W[K,N] + bias[N]   (M=4096, N=K=1024)  — unchanged
// (validated rounds 4 and 7)
template<int OUT_MODE>
__global__ __launch_bounds__(256)
void gemm_kernel(const float* __restrict__ A, const float* __restrict__ W,
                 const float* __restrict__ bias, float* __restrict__ C)
{
    constexpr int M = BB * SS, N = HIDD, K = HIDD;
    constexpr int BM = 128, BN = 64, BK = 16, NK = K / BK;
    constexpr int LDA = 132, LDW = 68;
    __shared__ float As[2][BK][LDA];
    __shared__ float Ws[2][BK][LDW];

    const int tid = threadIdx.x;
    const int tx = tid & 15, ty = tid >> 4;

    const int swz = (blockIdx.x & 7) * 64 + (blockIdx.x >> 3);
    const int n0 = (swz & 15) * BN;
    const int m0 = (swz >> 4) * BM;

    const int a_m = tid >> 2;
    const int a_k = (tid & 3) * 4;
    const int w_k = tid >> 4;
    const int w_n = (tid & 15) * 4;

    const float* Abase = A + (size_t)m0 * K;
    const float* Wbase = W + n0;

    f4 pa0, pa1, pw0;

#define G_LOAD(kt) {                                                        \
    const float* Ap = Abase + (size_t)(kt) * BK + a_k;                      \
    pa0 = *(const f4*)(Ap + (size_t)a_m * K);                               \
    pa1 = *(const f4*)(Ap + (size_t)(a_m + 64) * K);                        \
    pw0 = *(const f4*)(Wbase + (size_t)((kt) * BK + w_k) * N + w_n); }

#define LDS_WRITE(buf) {                                                    \
    As[buf][a_k+0][a_m]      = pa0[0]; As[buf][a_k+1][a_m]      = pa0[1];   \
    As[buf][a_k+2][a_m]      = pa0[2]; As[buf][a_k+3][a_m]      = pa0[3];   \
    As[buf][a_k+0][a_m+64]   = pa1[0]; As[buf][a_k+1][a_m+64]   = pa1[1];   \
    As[buf][a_k+2][a_m+64]   = pa1[2]; As[buf][a_k+3][a_m+64]   = pa1[3];   \
    *(f4*)&Ws[buf][w_k][w_n] = pw0; }

    float acc[8][4] = {};

    G_LOAD(0);
    LDS_WRITE(0);
    __syncthreads();

    int cur = 0;
    for (int kt = 0; kt < NK; ++kt) {
        if (kt + 1 < NK) G_LOAD(kt + 1);
        #pragma unroll 4
        for (int k = 0; k < BK; ++k) {
            f4 af0 = *(const f4*)&As[cur][k][4 * ty];
            f4 af1 = *(const f4*)&As[cur][k][64 + 4 * ty];
            f4 bf  = *(const f4*)&Ws[cur][k][4 * tx];
            #pragma unroll
            for (int i = 0; i < 4; ++i) {
                #pragma unroll
                for (int j = 0; j < 4; ++j) {
                    acc[i][j]   = fmaf(af0[i], bf[j], acc[i][j]);
                    acc[i+4][j] = fmaf(af1[i], bf[j], acc[i+4][j]);
                }
            }
        }
        if (kt + 1 < NK) LDS_WRITE(cur ^ 1);
        __syncthreads();
        cur ^= 1;
    }

    f4 biasv = *(const f4*)&bias[n0 + 4 * tx];
    #pragma unroll
    for (int i = 0; i < 8; ++i) {
        const int m = m0 + 4 * ty + ((i < 4) ? i : (64 + i - 4));
        f4 v;
        #pragma unroll
        for (int j = 0; j < 4; ++j) v[j] = acc[i][j] + biasv[j];
        if (OUT_MODE == 0) {
            *(f4*)(C + (size_t)m * N + n0 + 4 * tx) = v;
        } else {
            const int b = m >> 11, s = m & (SS - 1);
            const int na = n0 + 4 * tx;
            float* da = C + ((size_t)(b * NHH + (na >> 6)) * SS + s) * HDD + (na & 63);
            *(f4*)da = v;
        }
    }
#undef G_LOAD
#undef LDS_WRITE
}

// ----------------------------------------------------------------------
// Flash attention, k=v=q, floored scores.
// QK^T: exact fp32 VALU from LDS (round-3/4 validated pattern, scores
// bit-identical -> floor flips unchanged). PV: bf16 2-split 3-term MFMA
// (mirrored frags + wave-private no-barrier P: validated round 7,
// absmax 0.015625); B-frags built on the fly from k_t f32 (V == K,
// k_t IS V^T) — no staged Vt, bit-identical MFMA inputs to staged.
// LDS 53248 B: q_s f32[64][68] + k_t f32[64][68] + P_hi/P_lo bf16[64][72].
// 3 blocks/CU by LDS (3x53248 = 159744 <= 163840); launch_bounds(256,3)
// caps VGPR at ~170 (est. live ~120) so 3 blocks land.
// Note: SQ_LDS_BANK_CONFLICT measured negligible (0.01% of CU-cycles,
// R4/R7) — conflict micro-opts are off the agenda.
__global__ __launch_bounds__(256, 3)
void attn_kernel(const float* __restrict__ q, float* __restrict__ o)
{
    __shared__ float q_s[64][68];
    __shared__ float k_t[64][68];
    __shared__ unsigned short P_hi[64][72];
    __shared__ unsigned short P_lo[64][72];

    const int tid = threadIdx.x;
    const int tx = tid & 15, ty = tid >> 4;
    const int lane = tid & 63;
    const int wv = tid >> 6;           // wave 0..3
    const int lr = lane & 15, lh = lane >> 4;

    // XCD-aware bijective remap: 1024 blocks = 8 XCDs x 128
    const int swzb = (blockIdx.x & 7) * 128 + (blockIdx.x >> 3);
    const int qb = swzb & 31;
    const int bh = swzb >> 5;

    const float* qhead = q + (size_t)bh * SS * 64;

    const int st_r = tid >> 2;             // row 0..63
    const int st_w = (tid & 3) * 4;        // d-chunk base

    // ---- Q tile -> LDS (prescaled by 1/8, exact pow2) ----
    {
        const float* src = qhead + (size_t)(qb * 64 + st_r) * 64 + st_w * 4;
        #pragma unroll
        for (int i = 0; i < 4; ++i) {
            f4 vq = *(const f4*)(src + 4 * i);
            #pragma unroll
            for (int j = 0; j < 4; ++j) vq[j] *= 0.125f;
            *(f4*)&q_s[st_r][(st_w + i) * 4] = vq;
        }
    }

    f4 acc[4] = {};   // MFMA C-frags: acc[ct][i] = O[4ty+i][16ct+lr]
    float m_r[4] = {-1e30f, -1e30f, -1e30f, -1e30f};
    float l_r[4] = {};

    f4 pk[4];
    {
        const float* src = qhead + (size_t)st_r * 64 + st_w * 4;
        #pragma unroll
        for (int i = 0; i < 4; ++i) pk[i] = *(const f4*)(src + 4 * i);
    }

    for (int kt = 0; kt < SS / 64; ++kt) {
        __syncthreads();   // prev tile done with k_t (QK + PV reads)
        // ---- stage K tile transposed (f32; serves QK-K and PV-V) ----
        #pragma unroll
        for (int i = 0; i < 4; ++i) {
            #pragma unroll
            for (int j = 0; j < 4; ++j) {
                k_t[(st_w + i) * 4 + j][st_r] = pk[i][j];
            }
        }
        __syncthreads();
        // prefetch next K tile (hidden under QK+softmax+PV)
        if (kt + 1 < SS / 64) {
            const float* src = qhead + (size_t)((kt + 1) * 64 + st_r) * 64 + st_w * 4;
            #pragma unroll
            for (int i = 0; i < 4; ++i) pk[i] = *(const f4*)(src + 4 * i);
        }

        // ---- QK^T (exact fp32): sc[i][j] = (q/8)[4ty+i] . k[4tx+j] ----
        float sc[4][4] = {};
        #pragma unroll 4
        for (int w = 0; w < 16; ++w) {
            f4 qf[4], kf[4];
            #pragma unroll
            for (int i = 0; i < 4; ++i) qf[i] = *(const f4*)&q_s[4 * ty + i][4 * w];
            #pragma unroll
            for (int l = 0; l < 4; ++l) kf[l] = *(const f4*)&k_t[4 * w + l][4 * tx];
            #pragma unroll
            for (int l = 0; l < 4; ++l)
                #pragma unroll
                for (int i = 0; i < 4; ++i)
                    #pragma unroll
                    for (int j = 0; j < 4; ++j)
                        sc[i][j] = fmaf(qf[i][l], kf[l][j], sc[i][j]);
        }

        // ---- floored scores + online softmax + P bf16 split -> LDS ----
        #pragma unroll
        for (int i = 0; i < 4; ++i) {
            #pragma unroll
            for (int j = 0; j < 4; ++j) sc[i][j] = floorf(sc[i][j]);
            float mx = fmaxf(fmaxf(sc[i][0], sc[i][1]), fmaxf(sc[i][2], sc[i][3]));
            #pragma unroll
            for (int s = 1; s < 16; s <<= 1) mx = fmaxf(mx, __shfl_xor(mx, s, 16));
            const float mn = fmaxf(m_r[i], mx);
            const float corr = __expf(m_r[i] - mn);
            m_r[i] = mn;
            float p[4], sum = 0.f;
            #pragma unroll
            for (int j = 0; j < 4; ++j) { p[j] = __expf(sc[i][j] - mn); sum += p[j]; }
            #pragma unroll
            for (int s = 1; s < 16; s <<= 1) sum += __shfl_xor(sum, s, 16);
            l_r[i] = l_r[i] * corr + sum;
            // rescale MFMA accumulators (D-reg i == softmax row 4ty+i)
            acc[0][i] *= corr; acc[1][i] *= corr; acc[2][i] *= corr; acc[3][i] *= corr;
            // split P to bf16 hi/lo, packed 8B writes
            unsigned short h0 = bf16_rne(p[0]), h1 = bf16_rne(p[1]);
            unsigned short h2 = bf16_rne(p[2]), h3 = bf16_rne(p[3]);
            uint2v uh, ul;
            uh[0] = (unsigned)h0 | ((unsigned)h1 << 16);
            uh[1] = (unsigned)h2 | ((unsigned)h3 << 16);
            unsigned short g0 = bf16_rne(p[0] - bf16_tof(h0));
            unsigned short g1 = bf16_rne(p[1] - bf16_tof(h1));
            unsigned short g2 = bf16_rne(p[2] - bf16_tof(h2));
            unsigned short g3 = bf16_rne(p[3] - bf16_tof(h3));
            ul[0] = (unsigned)g0 | ((unsigned)g1 << 16);
            ul[1] = (unsigned)g2 | ((unsigned)g3 << 16);
            *(uint2v*)&P_hi[4 * ty + i][4 * tx] = uh;
            *(uint2v*)&P_lo[4 * ty + i][4 * tx] = ul;
        }
        // NO barrier: P is wave-private (written by ty in [4wv,4wv+4),
        // read as A-frags rows 16wv+lr — same wave). Within-wave LDS
        // RAW ordering enforced by compiler lgkmcnt. (Validated R7.)

        // ---- PV via MFMA: A = P (split, from LDS), B = V^T = k_t (f32,
        //      split to bf16 in-register). 3-term x 2 k-halves x 4 ct. ----
        const int prow = 16 * wv + lr;
        short8 ah0 = *(const short8*)&P_hi[prow][lh * 8];
        short8 ah1 = *(const short8*)&P_hi[prow][32 + lh * 8];
        short8 al0 = *(const short8*)&P_lo[prow][lh * 8];
        short8 al1 = *(const short8*)&P_lo[prow][32 + lh * 8];
        #pragma unroll
        for (int ct = 0; ct < 4; ++ct) {
            const float* vp = &k_t[16 * ct + lr][0];
            bfrag b0 = split8(*(const f4*)(vp + lh * 8),
                              *(const f4*)(vp + lh * 8 + 4));
            bfrag b1 = split8(*(const f4*)(vp + 32 + lh * 8),
                              *(const f4*)(vp + 32 + lh * 8 + 4));
            acc[ct] = __builtin_amdgcn_mfma_f32_16x16x32_bf16(ah0, b0.hi, acc[ct], 0, 0, 0);
            acc[ct] = __builtin_amdgcn_mfma_f32_16x16x32_bf16(al0, b0.hi, acc[ct], 0, 0, 0);
            acc[ct] = __builtin_amdgcn_mfma_f32_16x16x32_bf16(ah0, b0.lo, acc[ct], 0, 0, 0);
            acc[ct] = __builtin_amdgcn_mfma_f32_16x16x32_bf16(ah1, b1.hi, acc[ct], 0, 0, 0);
            acc[ct] = __builtin_amdgcn_mfma_f32_16x16x32_bf16(al1, b1.hi, acc[ct], 0, 0, 0);
            acc[ct] = __builtin_amdgcn_mfma_f32_16x16x32_bf16(ah1, b1.lo, acc[ct], 0, 0, 0);
        }
    }

    // ---- epilogue: normalize rows, write o[b][s][h*64 + 16ct + lr] ----
    const int b = bh >> 4, h = bh & 15;
    #pragma unroll
    for (int i = 0; i < 4; ++i) {
        const float inv = 1.0f / l_r[i];
        const int srow = qb * 64 + 4 * ty + i;
        float* orow = o + ((size_t)(b * SS + srow)) * HIDD + h * 64;
        #pragma unroll
        for (int ct = 0; ct < 4; ++ct)
            orow[16 * ct + lr] = acc[ct][i] * inv;
    }
}

// ----------------------------------------------------------------------
extern "C" void kernel_launch(void* const* d_in, const int* in_sizes, int n_in,
                              void* d_out, int out_size, void* d_ws, size_t ws_size,
                              hipStream_t stream)
{
    const float* x  = (const float*)d_in[0];
    const float* Wq = (const float*)d_in[1];
    const float* bq = (const float*)d_in[2];
    const float* Wo = (const float*)d_in[3];
    const float* bo = (const float*)d_in[4];
    float* out = (float*)d_out;

    float* q_ws    = (float*)d_ws;                       // [B*NH][S][64] = 16 MB
    float* attn_ws = q_ws + (size_t)BB * SS * HIDD;      // [B][S][HID]   = 16 MB

    gemm_kernel<1><<<512, 256, 0, stream>>>(x, Wq, bq, q_ws);
    attn_kernel<<<1024, 256, 0, stream>>>(q_ws, attn_ws);
    gemm_kernel<0><<<512, 256, 0, stream>>>(attn_ws, Wo, bo, out);
}